// Round 15
// baseline (1328.567 us; speedup 1.0000x reference)
//
#include <hip/hip_runtime.h>
#include <stdint.h>

// AWQ 4-bit dequant GEMM: out[M,N] = x[M,K] @ W[N,K]^T + bias
// Path 2 (ws >= X+W): prepass x->fp16 (row-major, pair-perm + period-4 swizzle)
//   and W->fp16 FRAG-MAJOR (1 KB per 16row x 32k frag-tile) into d_ws.
//   GEMM: BM=256 BN=128 BK=32, 512 thr (8 waves 4Mx2N of 64x64).
//   A: glds->LDS triple-buffer (48 KB -> 2 blocks/CU).
//   B: direct global->reg, PARITY DOUBLE-BUFFER (bqA/bqB): tile t refills the
//   set it just consumed for t+2 -> 2-tile latency cover (fixes R14's exposed
//   B-load stall). A-frags streamed singly to keep unified regs <=128.
//   Tile end: s_waitcnt vmcnt(6) + s_barrier (counted; only tail drains 0).

typedef _Float16 f16x2 __attribute__((ext_vector_type(2)));
typedef _Float16 f16x8 __attribute__((ext_vector_type(8)));
typedef float f32x4 __attribute__((ext_vector_type(4)));
typedef unsigned int u32x4 __attribute__((ext_vector_type(4)));

// ---------- prepass: x -> fp16 row-major, pair-perm, period-4 swizzle --------
__global__ void convert_x2_kernel(const float* __restrict__ x,
                                  unsigned short* __restrict__ xh,
                                  int M, int K) {
    int g = blockIdx.x * blockDim.x + threadIdx.x;
    int kc = K >> 3;
    if (g >= M * kc) return;
    int r  = g / kc;
    int cc = g - r * kc;
    int csrc = (cc & ~3) | ((cc & 3) ^ ((r >> 1) & 3));
    const float* p = x + (size_t)r * K + (csrc << 3);
    float4 f0 = *reinterpret_cast<const float4*>(p);
    float4 f1 = *reinterpret_cast<const float4*>(p + 4);
    u32x4 o;
    o.x = __builtin_bit_cast(uint32_t, __builtin_amdgcn_cvt_pkrtz(f0.x, f1.x));
    o.y = __builtin_bit_cast(uint32_t, __builtin_amdgcn_cvt_pkrtz(f0.y, f1.y));
    o.z = __builtin_bit_cast(uint32_t, __builtin_amdgcn_cvt_pkrtz(f0.z, f1.z));
    o.w = __builtin_bit_cast(uint32_t, __builtin_amdgcn_cvt_pkrtz(f0.w, f1.w));
    u32x4* dst = reinterpret_cast<u32x4*>(xh + (size_t)r * K + (cc << 3));
    __builtin_nontemporal_store(o, dst);
}

// ---------- prepass: W int4 -> fp16 FRAG-MAJOR dequant (layout verified R14) -
__global__ void convert_w3_kernel(const int* __restrict__ qw,
                                  const int* __restrict__ qz,
                                  const float* __restrict__ sc,
                                  unsigned short* __restrict__ whf,
                                  int Nrows, int K) {
    int d = blockIdx.x * blockDim.x + threadIdx.x;
    int kt32 = K >> 5;
    int total = Nrows * (K >> 3);
    if (d >= total) return;
    int l   = d & 63;
    int rest = d >> 6;
    int kt  = rest % kt32;
    int gg  = rest / kt32;
    int o   = gg * 16 + (l & 15);
    int c   = l >> 4;
    int ngrp = K >> 7, nzw = ngrp >> 3;
    int grp = kt >> 2;
    float s = sc[(size_t)o * ngrp + grp];
    uint32_t z = ((uint32_t)qz[(size_t)o * nzw + (grp >> 3)] >> ((grp & 7) << 2)) & 0xF;
    uint32_t u = (uint32_t)qw[(size_t)o * (K >> 3) + kt * 4 + c];
    _Float16 hs = (_Float16)s;
    _Float16 hz = (_Float16)(1024.0f + (float)z);   // integer <=1039: exact fp16
    f16x2 s2 = {hs, hs}, z2 = {hz, hz};
    const uint32_t MK = 0x000F000Fu, MG = 0x64006400u;
    uint32_t p0 = (u & MK) | MG;
    uint32_t p1 = ((u >> 4) & MK) | MG;
    uint32_t p2 = ((u >> 8) & MK) | MG;
    uint32_t p3 = ((u >> 12) & MK) | MG;
    u32x4 ov;
    ov.x = __builtin_bit_cast(uint32_t, (__builtin_bit_cast(f16x2, p0) - z2) * s2);
    ov.y = __builtin_bit_cast(uint32_t, (__builtin_bit_cast(f16x2, p1) - z2) * s2);
    ov.z = __builtin_bit_cast(uint32_t, (__builtin_bit_cast(f16x2, p2) - z2) * s2);
    ov.w = __builtin_bit_cast(uint32_t, (__builtin_bit_cast(f16x2, p3) - z2) * s2);
    __builtin_nontemporal_store(ov, reinterpret_cast<u32x4*>(whf + (size_t)d * 8));
}

// ---------- path 2 GEMM: A via LDS, B reg parity-double-buffered -------------
__global__ __launch_bounds__(512, 4) void awq_gemm2_kernel(
    const unsigned short* __restrict__ xh,
    const unsigned short* __restrict__ whf,
    const float* __restrict__ bias,
    float* __restrict__ out,
    int M, int N, int K)
{
    extern __shared__ __align__(16) unsigned short lds[];
    const int ATSZ = 256 * 32;                // 16 KB per A buffer
    unsigned short* As = lds;                 // [3][ATSZ]

    const int tid  = threadIdx.x;
    const int lane = tid & 63;
    const int wave = tid >> 6;
    const int wr   = wave & 3;                // 64-row quarter of 256
    const int wc   = wave >> 2;               // 64-col half of 128
    const int lrow = lane & 15;
    const int cswz = (((lane >> 4) ^ ((lrow >> 1) & 3)) << 3);

    const int cpx = gridDim.x >> 3;
    const int bid = (blockIdx.x & 7) * cpx + (blockIdx.x >> 3);
    const int ntn = N / 128;                  // 32
    const int m0 = (bid / ntn) * 256;
    const int n0 = (bid % ntn) * 128;
    const int NT = K / 32;                    // 128 (even; K mult of 128)
    const int kt32 = K >> 5;

    f32x4 acc[4][4];
    #pragma unroll
    for (int m = 0; m < 4; ++m)
        #pragma unroll
        for (int n = 0; n < 4; ++n)
            #pragma unroll
            for (int e = 0; e < 4; ++e) acc[m][n][e] = 0.f;

    // B frag-tile base (group g = n0/16 + wc*4 + n; frag n offset n*kt32*512)
    const unsigned short* bb0 = whf + ((size_t)((n0 >> 4) + wc * 4) * kt32) * 512 + lane * 8;
    const size_t bstride = (size_t)kt32 * 512;

    auto GLDSA = [&](int kt, unsigned short* dst) {
        #pragma unroll
        for (int i = 0; i < 2; ++i) {
            int row = wave * 32 + i * 16 + (lane >> 2);
            const unsigned short* g = xh + (size_t)(m0 + row) * K + kt + ((lane & 3) << 3);
            unsigned short* d = dst + row * 32 + ((lane & 3) << 3);
            __builtin_amdgcn_global_load_lds(
                (const __attribute__((address_space(1))) unsigned int*)g,
                (__attribute__((address_space(3))) unsigned int*)d, 16, 0, 0);
        }
    };

    uint4 bqA[4], bqB[4];
    auto LOADB = [&](int kt, uint4* bq) {
        #pragma unroll
        for (int n = 0; n < 4; ++n)
            bq[n] = *reinterpret_cast<const uint4*>(bb0 + n * bstride + (size_t)kt * 512);
    };

    // one tile's compute + next-next staging (bq = parity buffer for tile t)
    auto TILE = [&](int t, uint4* bq) {
        const unsigned short* Ab = As + (t % 3) * ATSZ;
        f16x8 bf[4];
        #pragma unroll
        for (int n = 0; n < 4; ++n) bf[n] = __builtin_bit_cast(f16x8, bq[n]);
        // stream A-frags singly: 4 regs live instead of 16
        #pragma unroll
        for (int m = 0; m < 4; ++m) {
            int row = wr * 64 + m * 16 + lrow;
            f16x8 a = __builtin_bit_cast(f16x8,
                      *reinterpret_cast<const uint4*>(&Ab[row * 32 + cswz]));
            #pragma unroll
            for (int n = 0; n < 4; ++n)
                acc[m][n] = __builtin_amdgcn_mfma_f32_16x16x32_f16(
                    a, bf[n], acc[m][n], 0, 0, 0);
        }
        if (t + 2 < NT) {
            LOADB(t + 2, bq);                         // refill SAME parity set
            GLDSA((t + 2) * 32, As + ((t + 2) % 3) * ATSZ);
            // newest 6 = the loads just issued; everything for t+1 retired.
            asm volatile("s_waitcnt vmcnt(6)" ::: "memory");
            __builtin_amdgcn_s_barrier();
        } else if (t + 1 < NT) {
            // nothing new issued; t+1's loads (issued at t-1) must land.
            asm volatile("s_waitcnt vmcnt(0)" ::: "memory");
            __builtin_amdgcn_s_barrier();
        }
        // last tile: fall through to epilogue
    };

    // ---- prologue: B(0)->bqA, B(1)->bqB; A tiles 0,1 -> LDS bufs 0,1
    LOADB(0, bqA);
    if (NT > 1) LOADB(1, bqB);
    GLDSA(0, As);
    if (NT > 1) GLDSA(32, As + ATSZ);
    asm volatile("s_waitcnt vmcnt(0)" ::: "memory");
    __syncthreads();

    for (int t = 0; t < NT; t += 2) {
        TILE(t, bqA);
        TILE(t + 1, bqB);
    }

    // epilogue: C frag col=lane&15, row=(lane>>4)*4+e
    const int r4 = (lane >> 4) << 2;
    #pragma unroll
    for (int n = 0; n < 4; ++n) {
        int col = n0 + wc * 64 + n * 16 + lrow;
        float bv = bias[col];
        #pragma unroll
        for (int m = 0; m < 4; ++m) {
            size_t rbase = (size_t)(m0 + wr * 64 + m * 16 + r4) * N + col;
            #pragma unroll
            for (int e = 0; e < 4; ++e)
                __builtin_nontemporal_store(acc[m][n][e] + bv, &out[rbase + (size_t)e * N]);
        }
    }
}

// ================= fallback (ws too small): R10-style reg-staged ============
#define BM 256
#define BN 256
#define BK 64

__global__ __launch_bounds__(512, 2) void awq_gemm0_kernel(
    const float* __restrict__ x,
    const int*   __restrict__ qw,
    const int*   __restrict__ qz,
    const float* __restrict__ sc,
    const float* __restrict__ bias,
    float*       __restrict__ out,
    int M, int N, int K)
{
    extern __shared__ __align__(16) unsigned short lds[];
    const int ASZ  = BM * BK;
    const int BPSZ = BN * (BK / 8);
    unsigned short* As = lds;
    uint32_t* Bp = reinterpret_cast<uint32_t*>(lds + 2 * ASZ);

    const int tid  = threadIdx.x;
    const int lane = tid & 63;
    const int wave = tid >> 6;
    const int wr   = wave >> 2;
    const int wc   = wave & 3;
    const int lrow = lane & 15;
    const int lko  = (lane >> 4) << 3;
    const int swr  = (lrow & 7) << 3;

    const int cpx = gridDim.x >> 3;
    const int bid = (blockIdx.x & 7) * cpx + (blockIdx.x >> 3);
    const int ntn = N / BN;
    const int m0 = (bid / ntn) * BM;
    const int n0 = (bid % ntn) * BN;

    const int ngrp = K >> 7;
    const int nzw  = ngrp >> 3;
    const int kw   = K >> 3;
    const int NT   = K / BK;

    const int r_s = tid >> 1;
    const int kh  = tid & 1;
    const int sws = (r_s & 7) << 3;

    f32x4 acc[8][4];
    #pragma unroll
    for (int m = 0; m < 8; ++m)
        #pragma unroll
        for (int n = 0; n < 4; ++n)
            #pragma unroll
            for (int e = 0; e < 4; ++e) acc[m][n][e] = 0.f;

    float    sc_pf[4];
    uint32_t zq_pf[4];
    f16x2    ss[4], zz[4];
    auto PFG = [&](int grp) {
        #pragma unroll
        for (int n = 0; n < 4; ++n) {
            int og = n0 + wc * 64 + n * 16 + lrow;
            sc_pf[n] = sc[(size_t)og * ngrp + grp];
            zq_pf[n] = (uint32_t)qz[(size_t)og * nzw + (grp >> 3)];
        }
    };
    auto SETG = [&](int grp) {
        #pragma unroll
        for (int n = 0; n < 4; ++n) {
            _Float16 s = (_Float16)sc_pf[n];
            uint32_t z = (zq_pf[n] >> ((grp & 7) << 2)) & 0xF;
            _Float16 Z = (_Float16)(float)(1024u + z);
            ss[n][0] = s; ss[n][1] = s;
            zz[n][0] = Z; zz[n][1] = Z;
        }
    };

    float4 a32[8];

    auto GLDSB = [&](int kt, uint32_t* Bw) {
        int row = tid >> 1;
        const int* g = qw + (size_t)(n0 + row) * kw + (kt >> 3) + (tid & 1) * 4;
        uint32_t* d = Bw + row * 8 + (tid & 1) * 4;
        __builtin_amdgcn_global_load_lds(
            (const __attribute__((address_space(1))) unsigned int*)g,
            (__attribute__((address_space(3))) unsigned int*)d, 16, 0, 0);
    };
    auto LOADA = [&](int kt) {
        const float* p = x + (size_t)(m0 + r_s) * K + kt + kh * 32;
        #pragma unroll
        for (int i = 0; i < 8; ++i)
            a32[i] = *reinterpret_cast<const float4*>(p + 4 * i);
    };
    auto WA = [&](unsigned short* dst, int c) {
        uint4 o;
        o.x = __builtin_bit_cast(uint32_t, __builtin_amdgcn_cvt_pkrtz(a32[2*c].x, a32[2*c+1].x));
        o.y = __builtin_bit_cast(uint32_t, __builtin_amdgcn_cvt_pkrtz(a32[2*c].y, a32[2*c+1].y));
        o.z = __builtin_bit_cast(uint32_t, __builtin_amdgcn_cvt_pkrtz(a32[2*c].z, a32[2*c+1].z));
        o.w = __builtin_bit_cast(uint32_t, __builtin_amdgcn_cvt_pkrtz(a32[2*c].w, a32[2*c+1].w));
        int kcol = kh * 32 + 8 * c;
        *reinterpret_cast<uint4*>(&dst[r_s * BK + (kcol ^ sws)]) = o;
    };

    f16x8 af[4], bfA[4], bfB[4];
    auto RDA = [&](const unsigned short* Ab, int mh, int kk) {
        #pragma unroll
        for (int m = 0; m < 4; ++m) {
            int arow = wr * 128 + (mh * 4 + m) * 16 + lrow;
            int idx = arow * BK + ((kk * 32 + lko) ^ swr);
            af[m] = __builtin_bit_cast(f16x8, *reinterpret_cast<const uint4*>(&Ab[idx]));
        }
    };
    auto DEQB = [&](const uint32_t* Bpb, f16x8* b, int kk) {
        const int dcol = kk * 4 + (lane >> 4);
        const uint32_t MK = 0x000F000Fu, MG = 0x64006400u;
        #pragma unroll
        for (int n = 0; n < 4; ++n) {
            int brow = wc * 64 + n * 16 + lrow;
            uint32_t u = Bpb[brow * 8 + dcol];
            uint32_t p0 = (u & MK) | MG;
            uint32_t p1 = ((u >> 4) & MK) | MG;
            uint32_t p2 = ((u >> 8) & MK) | MG;
            uint32_t p3 = ((u >> 12) & MK) | MG;
            u32x4 o;
            o.x = __builtin_bit_cast(uint32_t, (__builtin_bit_cast(f16x2, p0) - zz[n]) * ss[n]);
            o.y = __builtin_bit_cast(uint32_t, (__builtin_bit_cast(f16x2, p1) - zz[n]) * ss[n]);
            o.z = __builtin_bit_cast(uint32_t, (__builtin_bit_cast(f16x2, p2) - zz[n]) * ss[n]);
            o.w = __builtin_bit_cast(uint32_t, (__builtin_bit_cast(f16x2, p3) - zz[n]) * ss[n]);
            b[n] = __builtin_bit_cast(f16x8, o);
        }
    };
    auto MFMAQ = [&](f16x8* bf, int mh) {
        #pragma unroll
        for (int m_ = 0; m_ < 4; ++m_)
            #pragma unroll
            for (int n_ = 0; n_ < 4; ++n_)
                acc[mh * 4 + m_][n_] = __builtin_amdgcn_mfma_f32_16x16x32_f16(
                    af[m_], bf[n_], acc[mh * 4 + m_][n_], 0, 0, 0);
    };

    PFG(0);
    GLDSB(0, Bp);
    LOADA(0);
    asm volatile("s_waitcnt vmcnt(0)" ::: "memory");
    #pragma unroll
    for (int c = 0; c < 4; ++c) WA(As, c);
    SETG(0);
    __syncthreads();

    for (int t = 0; t < NT; ++t) {
        const int grp = t >> 1;
        if (t && !(t & 1)) SETG(grp);
        if ((t & 1) && grp + 1 < ngrp) PFG(grp + 1);

        const int buf = t & 1;
        const unsigned short* Ab = As + buf * ASZ;
        const uint32_t* Bpb = Bp + buf * BPSZ;
        if (t + 1 < NT) {
            GLDSB((t + 1) * BK, Bp + (buf ^ 1) * BPSZ);
            LOADA((t + 1) * BK);
        }

        DEQB(Bpb, bfA, 0);
        RDA(Ab, 0, 0);
        MFMAQ(bfA, 0);
        RDA(Ab, 1, 0);
        MFMAQ(bfA, 1);
        DEQB(Bpb, bfB, 1);
        RDA(Ab, 0, 1);
        MFMAQ(bfB, 0);
        RDA(Ab, 1, 1);
        MFMAQ(bfB, 1);

        if (t + 1 < NT) { WA(As + (buf ^ 1) * ASZ, 0); WA(As + (buf ^ 1) * ASZ, 1);
                          WA(As + (buf ^ 1) * ASZ, 2); WA(As + (buf ^ 1) * ASZ, 3); }
        __syncthreads();
    }

    const int r4 = (lane >> 4) << 2;
    #pragma unroll
    for (int n = 0; n < 4; ++n) {
        int col = n0 + wc * 64 + n * 16 + lrow;
        float bv = bias[col];
        #pragma unroll
        for (int m = 0; m < 8; ++m) {
            size_t rbase = (size_t)(m0 + wr * 128 + m * 16 + r4) * N + col;
            #pragma unroll
            for (int e = 0; e < 4; ++e)
                __builtin_nontemporal_store(acc[m][n][e] + bv, &out[rbase + (size_t)e * N]);
        }
    }
}

extern "C" void kernel_launch(void* const* d_in, const int* in_sizes, int n_in,
                              void* d_out, int out_size, void* d_ws, size_t ws_size,
                              hipStream_t stream) {
    const float* x   = (const float*)d_in[0];
    const int*   qwp = (const int*)d_in[1];
    const int*   qzp = (const int*)d_in[2];
    const float* scp = (const float*)d_in[3];
    const float* bp  = (const float*)d_in[4];
    float* outp = (float*)d_out;

    const int N = in_sizes[4];                 // 4096 (O)
    const int K = (in_sizes[1] / N) * 8;       // 4096 (I)
    const int M = in_sizes[0] / K;             // 8192 (B)

    dim3 block(512);
    const size_t needX = (size_t)M * K * 2;
    const size_t needW = (size_t)N * K * 2;

    if (ws_size >= needX + needW) {
        unsigned short* xh  = (unsigned short*)d_ws;
        unsigned short* whf = xh + (size_t)M * K;
        int ncx = M * (K / 8), ncw = N * (K / 8);
        convert_x2_kernel<<<dim3((ncx + 255) / 256), dim3(256), 0, stream>>>(x, xh, M, K);
        convert_w3_kernel<<<dim3((ncw + 255) / 256), dim3(256), 0, stream>>>(qwp, qzp, scp, whf, N, K);
        dim3 grid2((M / 256) * (N / 128));     // 1024
        const int ldsbytes = 3 * 256 * 32 * 2; // 48 KB -> 2 blocks/CU
        (void)hipFuncSetAttribute(
            reinterpret_cast<const void*>(&awq_gemm2_kernel),
            hipFuncAttributeMaxDynamicSharedMemorySize, ldsbytes);
        awq_gemm2_kernel<<<grid2, block, ldsbytes, stream>>>(xh, whf, bp, outp, M, N, K);
    } else {
        dim3 grid((M / BM) * (N / BN));
        const int ldsbytes = 2 * BM * BK * 2 + 2 * BN * (BK / 8) * 4;
        (void)hipFuncSetAttribute(
            reinterpret_cast<const void*>(&awq_gemm0_kernel),
            hipFuncAttributeMaxDynamicSharedMemorySize, ldsbytes);
        awq_gemm0_kernel<<<grid, block, ldsbytes, stream>>>(
            x, qwp, qzp, scp, bp, outp, M, N, K);
    }
}

// Round 16
// 531.569 us; speedup vs baseline: 2.4993x; 2.4993x over previous
//
#include <hip/hip_runtime.h>
#include <stdint.h>

// AWQ 4-bit dequant GEMM: out[M,N] = x[M,K] @ W[N,K]^T + bias
// Path 2 (ws >= X+W): prepass x->fp16 (row-major, pair-perm + period-4 swizzle)
//   and W->fp16 FRAG-MAJOR (1 KB per 16row x 32k frag-tile) into d_ws.
//   GEMM: BM=256 BN=128 BK=32, 512 thr (8 waves 4Mx2N of 64x64).
//   A: glds->LDS triple-buffer (48 KB -> 2 blocks/CU).
//   B: direct global->reg, parity double-buffer bqA/bqB -- accessed ONLY via
//   macros with the STATIC array name (R15 used lambda pointer params ->
//   rule-#20 scratch spill, 2.7 GB of scratch traffic). 2-tile B prefetch
//   distance; tile end s_waitcnt vmcnt(6) + s_barrier (counted).

typedef _Float16 f16x2 __attribute__((ext_vector_type(2)));
typedef _Float16 f16x8 __attribute__((ext_vector_type(8)));
typedef float f32x4 __attribute__((ext_vector_type(4)));
typedef unsigned int u32x4 __attribute__((ext_vector_type(4)));

// ---------- prepass: x -> fp16 row-major, pair-perm, period-4 swizzle --------
__global__ void convert_x2_kernel(const float* __restrict__ x,
                                  unsigned short* __restrict__ xh,
                                  int M, int K) {
    int g = blockIdx.x * blockDim.x + threadIdx.x;
    int kc = K >> 3;
    if (g >= M * kc) return;
    int r  = g / kc;
    int cc = g - r * kc;
    int csrc = (cc & ~3) | ((cc & 3) ^ ((r >> 1) & 3));
    const float* p = x + (size_t)r * K + (csrc << 3);
    float4 f0 = *reinterpret_cast<const float4*>(p);
    float4 f1 = *reinterpret_cast<const float4*>(p + 4);
    u32x4 o;
    o.x = __builtin_bit_cast(uint32_t, __builtin_amdgcn_cvt_pkrtz(f0.x, f1.x));
    o.y = __builtin_bit_cast(uint32_t, __builtin_amdgcn_cvt_pkrtz(f0.y, f1.y));
    o.z = __builtin_bit_cast(uint32_t, __builtin_amdgcn_cvt_pkrtz(f0.z, f1.z));
    o.w = __builtin_bit_cast(uint32_t, __builtin_amdgcn_cvt_pkrtz(f0.w, f1.w));
    u32x4* dst = reinterpret_cast<u32x4*>(xh + (size_t)r * K + (cc << 3));
    __builtin_nontemporal_store(o, dst);
}

// ---------- prepass: W int4 -> fp16 FRAG-MAJOR dequant (layout verified R14) -
__global__ void convert_w3_kernel(const int* __restrict__ qw,
                                  const int* __restrict__ qz,
                                  const float* __restrict__ sc,
                                  unsigned short* __restrict__ whf,
                                  int Nrows, int K) {
    int d = blockIdx.x * blockDim.x + threadIdx.x;
    int kt32 = K >> 5;
    int total = Nrows * (K >> 3);
    if (d >= total) return;
    int l   = d & 63;
    int rest = d >> 6;
    int kt  = rest % kt32;
    int gg  = rest / kt32;
    int o   = gg * 16 + (l & 15);
    int c   = l >> 4;
    int ngrp = K >> 7, nzw = ngrp >> 3;
    int grp = kt >> 2;
    float s = sc[(size_t)o * ngrp + grp];
    uint32_t z = ((uint32_t)qz[(size_t)o * nzw + (grp >> 3)] >> ((grp & 7) << 2)) & 0xF;
    uint32_t u = (uint32_t)qw[(size_t)o * (K >> 3) + kt * 4 + c];
    _Float16 hs = (_Float16)s;
    _Float16 hz = (_Float16)(1024.0f + (float)z);   // integer <=1039: exact fp16
    f16x2 s2 = {hs, hs}, z2 = {hz, hz};
    const uint32_t MK = 0x000F000Fu, MG = 0x64006400u;
    uint32_t p0 = (u & MK) | MG;
    uint32_t p1 = ((u >> 4) & MK) | MG;
    uint32_t p2 = ((u >> 8) & MK) | MG;
    uint32_t p3 = ((u >> 12) & MK) | MG;
    u32x4 ov;
    ov.x = __builtin_bit_cast(uint32_t, (__builtin_bit_cast(f16x2, p0) - z2) * s2);
    ov.y = __builtin_bit_cast(uint32_t, (__builtin_bit_cast(f16x2, p1) - z2) * s2);
    ov.z = __builtin_bit_cast(uint32_t, (__builtin_bit_cast(f16x2, p2) - z2) * s2);
    ov.w = __builtin_bit_cast(uint32_t, (__builtin_bit_cast(f16x2, p3) - z2) * s2);
    __builtin_nontemporal_store(ov, reinterpret_cast<u32x4*>(whf + (size_t)d * 8));
}

// ---------- path 2 GEMM: A via LDS, B reg parity-double-buffered (macros) ----
__global__ __launch_bounds__(512, 4) void awq_gemm2_kernel(
    const unsigned short* __restrict__ xh,
    const unsigned short* __restrict__ whf,
    const float* __restrict__ bias,
    float* __restrict__ out,
    int M, int N, int K)
{
    extern __shared__ __align__(16) unsigned short lds[];
    const int ATSZ = 256 * 32;                // 16 KB per A buffer
    unsigned short* As = lds;                 // [3][ATSZ]

    const int tid  = threadIdx.x;
    const int lane = tid & 63;
    const int wave = tid >> 6;
    const int wr   = wave & 3;                // 64-row quarter of 256
    const int wc   = wave >> 2;               // 64-col half of 128
    const int lrow = lane & 15;
    const int cswz = (((lane >> 4) ^ ((lrow >> 1) & 3)) << 3);

    const int cpx = gridDim.x >> 3;
    const int bid = (blockIdx.x & 7) * cpx + (blockIdx.x >> 3);
    const int ntn = N / 128;                  // 32
    const int m0 = (bid / ntn) * 256;
    const int n0 = (bid % ntn) * 128;
    const int NT = K / 32;                    // 128 (even)
    const int kt32 = K >> 5;

    f32x4 acc[4][4];
    #pragma unroll
    for (int m = 0; m < 4; ++m)
        #pragma unroll
        for (int n = 0; n < 4; ++n)
            #pragma unroll
            for (int e = 0; e < 4; ++e) acc[m][n][e] = 0.f;

    const unsigned short* bb0 = whf + ((size_t)((n0 >> 4) + wc * 4) * kt32) * 512 + lane * 8;
    const size_t bstride = (size_t)kt32 * 512;

    auto GLDSA = [&](int kt, unsigned short* dst) {
        #pragma unroll
        for (int i = 0; i < 2; ++i) {
            int row = wave * 32 + i * 16 + (lane >> 2);
            const unsigned short* g = xh + (size_t)(m0 + row) * K + kt + ((lane & 3) << 3);
            unsigned short* d = dst + row * 32 + ((lane & 3) << 3);
            __builtin_amdgcn_global_load_lds(
                (const __attribute__((address_space(1))) unsigned int*)g,
                (__attribute__((address_space(3))) unsigned int*)d, 16, 0, 0);
        }
    };

    uint4 bqA[4], bqB[4];   // parity buffers: ONLY touched via static-name macros

#define LOADB_TO(bq, kt)                                                      \
    _Pragma("unroll")                                                         \
    for (int n_ = 0; n_ < 4; ++n_)                                            \
        bq[n_] = *reinterpret_cast<const uint4*>(                             \
            bb0 + n_ * bstride + (size_t)(kt) * 512);

#define TILE_M(t, bq)                                                         \
    {                                                                         \
        const unsigned short* Ab_ = As + ((t) % 3) * ATSZ;                    \
        _Pragma("unroll")                                                     \
        for (int m_ = 0; m_ < 4; ++m_) {                                      \
            int row_ = wr * 64 + m_ * 16 + lrow;                              \
            f16x8 a_ = __builtin_bit_cast(f16x8,                              \
                *reinterpret_cast<const uint4*>(&Ab_[row_ * 32 + cswz]));     \
            _Pragma("unroll")                                                 \
            for (int n_ = 0; n_ < 4; ++n_)                                    \
                acc[m_][n_] = __builtin_amdgcn_mfma_f32_16x16x32_f16(         \
                    a_, __builtin_bit_cast(f16x8, bq[n_]), acc[m_][n_],       \
                    0, 0, 0);                                                 \
        }                                                                     \
        if ((t) + 2 < NT) {                                                   \
            LOADB_TO(bq, (t) + 2)                                             \
            GLDSA(((t) + 2) * 32, As + (((t) + 2) % 3) * ATSZ);               \
            asm volatile("s_waitcnt vmcnt(6)" ::: "memory");                  \
            __builtin_amdgcn_s_barrier();                                     \
        } else if ((t) + 1 < NT) {                                            \
            asm volatile("s_waitcnt vmcnt(0)" ::: "memory");                  \
            __builtin_amdgcn_s_barrier();                                     \
        }                                                                     \
    }

    // ---- prologue: B(0)->bqA, B(1)->bqB; A tiles 0,1 -> LDS bufs 0,1
    LOADB_TO(bqA, 0)
    LOADB_TO(bqB, 1)
    GLDSA(0, As);
    GLDSA(32, As + ATSZ);
    asm volatile("s_waitcnt vmcnt(0)" ::: "memory");
    __syncthreads();

    for (int t = 0; t < NT; t += 2) {
        TILE_M(t, bqA)
        TILE_M(t + 1, bqB)
    }
#undef TILE_M
#undef LOADB_TO

    // epilogue: C frag col=lane&15, row=(lane>>4)*4+e
    const int r4 = (lane >> 4) << 2;
    #pragma unroll
    for (int n = 0; n < 4; ++n) {
        int col = n0 + wc * 64 + n * 16 + lrow;
        float bv = bias[col];
        #pragma unroll
        for (int m = 0; m < 4; ++m) {
            size_t rbase = (size_t)(m0 + wr * 64 + m * 16 + r4) * N + col;
            #pragma unroll
            for (int e = 0; e < 4; ++e)
                __builtin_nontemporal_store(acc[m][n][e] + bv, &out[rbase + (size_t)e * N]);
        }
    }
}

// ================= fallback (ws too small): R10-style reg-staged ============
#define BM 256
#define BN 256
#define BK 64

__global__ __launch_bounds__(512, 2) void awq_gemm0_kernel(
    const float* __restrict__ x,
    const int*   __restrict__ qw,
    const int*   __restrict__ qz,
    const float* __restrict__ sc,
    const float* __restrict__ bias,
    float*       __restrict__ out,
    int M, int N, int K)
{
    extern __shared__ __align__(16) unsigned short lds[];
    const int ASZ  = BM * BK;
    const int BPSZ = BN * (BK / 8);
    unsigned short* As = lds;
    uint32_t* Bp = reinterpret_cast<uint32_t*>(lds + 2 * ASZ);

    const int tid  = threadIdx.x;
    const int lane = tid & 63;
    const int wave = tid >> 6;
    const int wr   = wave >> 2;
    const int wc   = wave & 3;
    const int lrow = lane & 15;
    const int lko  = (lane >> 4) << 3;
    const int swr  = (lrow & 7) << 3;

    const int cpx = gridDim.x >> 3;
    const int bid = (blockIdx.x & 7) * cpx + (blockIdx.x >> 3);
    const int ntn = N / BN;
    const int m0 = (bid / ntn) * BM;
    const int n0 = (bid % ntn) * BN;

    const int ngrp = K >> 7;
    const int nzw  = ngrp >> 3;
    const int kw   = K >> 3;
    const int NT   = K / BK;

    const int r_s = tid >> 1;
    const int kh  = tid & 1;
    const int sws = (r_s & 7) << 3;

    f32x4 acc[8][4];
    #pragma unroll
    for (int m = 0; m < 8; ++m)
        #pragma unroll
        for (int n = 0; n < 4; ++n)
            #pragma unroll
            for (int e = 0; e < 4; ++e) acc[m][n][e] = 0.f;

    float    sc_pf[4];
    uint32_t zq_pf[4];
    f16x2    ss[4], zz[4];
    auto PFG = [&](int grp) {
        #pragma unroll
        for (int n = 0; n < 4; ++n) {
            int og = n0 + wc * 64 + n * 16 + lrow;
            sc_pf[n] = sc[(size_t)og * ngrp + grp];
            zq_pf[n] = (uint32_t)qz[(size_t)og * nzw + (grp >> 3)];
        }
    };
    auto SETG = [&](int grp) {
        #pragma unroll
        for (int n = 0; n < 4; ++n) {
            _Float16 s = (_Float16)sc_pf[n];
            uint32_t z = (zq_pf[n] >> ((grp & 7) << 2)) & 0xF;
            _Float16 Z = (_Float16)(float)(1024u + z);
            ss[n][0] = s; ss[n][1] = s;
            zz[n][0] = Z; zz[n][1] = Z;
        }
    };

    float4 a32[8];

    auto GLDSB = [&](int kt, uint32_t* Bw) {
        int row = tid >> 1;
        const int* g = qw + (size_t)(n0 + row) * kw + (kt >> 3) + (tid & 1) * 4;
        uint32_t* d = Bw + row * 8 + (tid & 1) * 4;
        __builtin_amdgcn_global_load_lds(
            (const __attribute__((address_space(1))) unsigned int*)g,
            (__attribute__((address_space(3))) unsigned int*)d, 16, 0, 0);
    };
    auto LOADA = [&](int kt) {
        const float* p = x + (size_t)(m0 + r_s) * K + kt + kh * 32;
        #pragma unroll
        for (int i = 0; i < 8; ++i)
            a32[i] = *reinterpret_cast<const float4*>(p + 4 * i);
    };
    auto WA = [&](unsigned short* dst, int c) {
        uint4 o;
        o.x = __builtin_bit_cast(uint32_t, __builtin_amdgcn_cvt_pkrtz(a32[2*c].x, a32[2*c+1].x));
        o.y = __builtin_bit_cast(uint32_t, __builtin_amdgcn_cvt_pkrtz(a32[2*c].y, a32[2*c+1].y));
        o.z = __builtin_bit_cast(uint32_t, __builtin_amdgcn_cvt_pkrtz(a32[2*c].z, a32[2*c+1].z));
        o.w = __builtin_bit_cast(uint32_t, __builtin_amdgcn_cvt_pkrtz(a32[2*c].w, a32[2*c+1].w));
        int kcol = kh * 32 + 8 * c;
        *reinterpret_cast<uint4*>(&dst[r_s * BK + (kcol ^ sws)]) = o;
    };

    f16x8 af[4], bfA[4], bfB[4];
    auto RDA = [&](const unsigned short* Ab, int mh, int kk) {
        #pragma unroll
        for (int m = 0; m < 4; ++m) {
            int arow = wr * 128 + (mh * 4 + m) * 16 + lrow;
            int idx = arow * BK + ((kk * 32 + lko) ^ swr);
            af[m] = __builtin_bit_cast(f16x8, *reinterpret_cast<const uint4*>(&Ab[idx]));
        }
    };
    auto DEQB = [&](const uint32_t* Bpb, f16x8* b, int kk) {
        const int dcol = kk * 4 + (lane >> 4);
        const uint32_t MK = 0x000F000Fu, MG = 0x64006400u;
        #pragma unroll
        for (int n = 0; n < 4; ++n) {
            int brow = wc * 64 + n * 16 + lrow;
            uint32_t u = Bpb[brow * 8 + dcol];
            uint32_t p0 = (u & MK) | MG;
            uint32_t p1 = ((u >> 4) & MK) | MG;
            uint32_t p2 = ((u >> 8) & MK) | MG;
            uint32_t p3 = ((u >> 12) & MK) | MG;
            u32x4 o;
            o.x = __builtin_bit_cast(uint32_t, (__builtin_bit_cast(f16x2, p0) - zz[n]) * ss[n]);
            o.y = __builtin_bit_cast(uint32_t, (__builtin_bit_cast(f16x2, p1) - zz[n]) * ss[n]);
            o.z = __builtin_bit_cast(uint32_t, (__builtin_bit_cast(f16x2, p2) - zz[n]) * ss[n]);
            o.w = __builtin_bit_cast(uint32_t, (__builtin_bit_cast(f16x2, p3) - zz[n]) * ss[n]);
            b[n] = __builtin_bit_cast(f16x8, o);
        }
    };
    auto MFMAQ = [&](f16x8* bf, int mh) {
        #pragma unroll
        for (int m_ = 0; m_ < 4; ++m_)
            #pragma unroll
            for (int n_ = 0; n_ < 4; ++n_)
                acc[mh * 4 + m_][n_] = __builtin_amdgcn_mfma_f32_16x16x32_f16(
                    af[m_], bf[n_], acc[mh * 4 + m_][n_], 0, 0, 0);
    };

    PFG(0);
    GLDSB(0, Bp);
    LOADA(0);
    asm volatile("s_waitcnt vmcnt(0)" ::: "memory");
    #pragma unroll
    for (int c = 0; c < 4; ++c) WA(As, c);
    SETG(0);
    __syncthreads();

    for (int t = 0; t < NT; ++t) {
        const int grp = t >> 1;
        if (t && !(t & 1)) SETG(grp);
        if ((t & 1) && grp + 1 < ngrp) PFG(grp + 1);

        const int buf = t & 1;
        const unsigned short* Ab = As + buf * ASZ;
        const uint32_t* Bpb = Bp + buf * BPSZ;
        if (t + 1 < NT) {
            GLDSB((t + 1) * BK, Bp + (buf ^ 1) * BPSZ);
            LOADA((t + 1) * BK);
        }

        DEQB(Bpb, bfA, 0);
        RDA(Ab, 0, 0);
        MFMAQ(bfA, 0);
        RDA(Ab, 1, 0);
        MFMAQ(bfA, 1);
        DEQB(Bpb, bfB, 1);
        RDA(Ab, 0, 1);
        MFMAQ(bfB, 0);
        RDA(Ab, 1, 1);
        MFMAQ(bfB, 1);

        if (t + 1 < NT) { WA(As + (buf ^ 1) * ASZ, 0); WA(As + (buf ^ 1) * ASZ, 1);
                          WA(As + (buf ^ 1) * ASZ, 2); WA(As + (buf ^ 1) * ASZ, 3); }
        __syncthreads();
    }

    const int r4 = (lane >> 4) << 2;
    #pragma unroll
    for (int n = 0; n < 4; ++n) {
        int col = n0 + wc * 64 + n * 16 + lrow;
        float bv = bias[col];
        #pragma unroll
        for (int m = 0; m < 8; ++m) {
            size_t rbase = (size_t)(m0 + wr * 128 + m * 16 + r4) * N + col;
            #pragma unroll
            for (int e = 0; e < 4; ++e)
                __builtin_nontemporal_store(acc[m][n][e] + bv, &out[rbase + (size_t)e * N]);
        }
    }
}

extern "C" void kernel_launch(void* const* d_in, const int* in_sizes, int n_in,
                              void* d_out, int out_size, void* d_ws, size_t ws_size,
                              hipStream_t stream) {
    const float* x   = (const float*)d_in[0];
    const int*   qwp = (const int*)d_in[1];
    const int*   qzp = (const int*)d_in[2];
    const float* scp = (const float*)d_in[3];
    const float* bp  = (const float*)d_in[4];
    float* outp = (float*)d_out;

    const int N = in_sizes[4];                 // 4096 (O)
    const int K = (in_sizes[1] / N) * 8;       // 4096 (I)
    const int M = in_sizes[0] / K;             // 8192 (B)

    dim3 block(512);
    const size_t needX = (size_t)M * K * 2;
    const size_t needW = (size_t)N * K * 2;

    if (ws_size >= needX + needW) {
        unsigned short* xh  = (unsigned short*)d_ws;
        unsigned short* whf = xh + (size_t)M * K;
        int ncx = M * (K / 8), ncw = N * (K / 8);
        convert_x2_kernel<<<dim3((ncx + 255) / 256), dim3(256), 0, stream>>>(x, xh, M, K);
        convert_w3_kernel<<<dim3((ncw + 255) / 256), dim3(256), 0, stream>>>(qwp, qzp, scp, whf, N, K);
        dim3 grid2((M / 256) * (N / 128));     // 1024
        const int ldsbytes = 3 * 256 * 32 * 2; // 48 KB -> 2 blocks/CU
        (void)hipFuncSetAttribute(
            reinterpret_cast<const void*>(&awq_gemm2_kernel),
            hipFuncAttributeMaxDynamicSharedMemorySize, ldsbytes);
        awq_gemm2_kernel<<<grid2, block, ldsbytes, stream>>>(xh, whf, bp, outp, M, N, K);
    } else {
        dim3 grid((M / BM) * (N / BN));
        const int ldsbytes = 2 * BM * BK * 2 + 2 * BN * (BK / 8) * 4;
        (void)hipFuncSetAttribute(
            reinterpret_cast<const void*>(&awq_gemm0_kernel),
            hipFuncAttributeMaxDynamicSharedMemorySize, ldsbytes);
        awq_gemm0_kernel<<<grid, block, ldsbytes, stream>>>(
            x, qwp, qzp, scp, bp, outp, M, N, K);
    }
}

// Round 17
// 407.263 us; speedup vs baseline: 3.2622x; 1.3052x over previous
//
#include <hip/hip_runtime.h>
#include <stdint.h>

// AWQ 4-bit dequant GEMM: out[M,N] = x[M,K] @ W[N,K]^T + bias
// Path 2 (ws >= X+W): prepass x->fp16 and W->fp16 (dequant) into d_ws,
//   row-major in 32-k tiles, pair-permuted, period-4 XOR swizzle baked
//   (R12-verified layout). GEMM = m201-style 8-PHASE schedule:
//   BM=BN=256, 512 thr (8 waves 2Mx4N, 128x64 per wave), acc[8][4].
//   LDS = 4 A-halfbufs + 4 B-halfbufs x 16KB = 128 KB (1 blk/CU).
//   Sub-tile u = 32 k. Iteration = 4 sub-tiles = 8 phases; phase =
//   {ds_read frags | stage 1 halfbuf (2 glds)} bar lgkm0 prio 16xMFMA prio bar.
//   vmcnt(4) ONLY at p3/p7 (counted, loads fly across barriers; proof in
//   comments); tail iterations vmcnt(0).
// Fallback: reg-staged fused kernel (no ws).

typedef _Float16 f16x2 __attribute__((ext_vector_type(2)));
typedef _Float16 f16x8 __attribute__((ext_vector_type(8)));
typedef float f32x4 __attribute__((ext_vector_type(4)));
typedef unsigned int u32x4 __attribute__((ext_vector_type(4)));

// ---------- prepass: x -> fp16 row-major, pair-perm, period-4 swizzle --------
__global__ void convert_x2_kernel(const float* __restrict__ x,
                                  unsigned short* __restrict__ xh,
                                  int M, int K) {
    int g = blockIdx.x * blockDim.x + threadIdx.x;
    int kc = K >> 3;
    if (g >= M * kc) return;
    int r  = g / kc;
    int cc = g - r * kc;
    int csrc = (cc & ~3) | ((cc & 3) ^ ((r >> 1) & 3));
    const float* p = x + (size_t)r * K + (csrc << 3);
    float4 f0 = *reinterpret_cast<const float4*>(p);
    float4 f1 = *reinterpret_cast<const float4*>(p + 4);
    u32x4 o;
    o.x = __builtin_bit_cast(uint32_t, __builtin_amdgcn_cvt_pkrtz(f0.x, f1.x));
    o.y = __builtin_bit_cast(uint32_t, __builtin_amdgcn_cvt_pkrtz(f0.y, f1.y));
    o.z = __builtin_bit_cast(uint32_t, __builtin_amdgcn_cvt_pkrtz(f0.z, f1.z));
    o.w = __builtin_bit_cast(uint32_t, __builtin_amdgcn_cvt_pkrtz(f0.w, f1.w));
    u32x4* dst = reinterpret_cast<u32x4*>(xh + (size_t)r * K + (cc << 3));
    __builtin_nontemporal_store(o, dst);
}

// ---------- prepass: W int4 -> fp16 dequant, same layout ---------------------
__global__ void convert_w2_kernel(const int* __restrict__ qw,
                                  const int* __restrict__ qz,
                                  const float* __restrict__ sc,
                                  unsigned short* __restrict__ wh,
                                  int Nrows, int K) {
    int g = blockIdx.x * blockDim.x + threadIdx.x;
    int kc = K >> 3;
    if (g >= Nrows * kc) return;
    int o  = g / kc;
    int cc = g - o * kc;
    int ngrp = K >> 7, nzw = ngrp >> 3;
    int grp = cc >> 4;
    float s = sc[(size_t)o * ngrp + grp];
    uint32_t z = ((uint32_t)qz[(size_t)o * nzw + (grp >> 3)] >> ((grp & 7) << 2)) & 0xF;
    uint32_t u = (uint32_t)qw[(size_t)o * kc + cc];
    _Float16 hs = (_Float16)s;
    _Float16 hz = (_Float16)(1024.0f + (float)z);   // integer <=1039: exact fp16
    f16x2 s2 = {hs, hs}, z2 = {hz, hz};
    const uint32_t MK = 0x000F000Fu, MG = 0x64006400u;
    uint32_t p0 = (u & MK) | MG;
    uint32_t p1 = ((u >> 4) & MK) | MG;
    uint32_t p2 = ((u >> 8) & MK) | MG;
    uint32_t p3 = ((u >> 12) & MK) | MG;
    u32x4 ov;
    ov.x = __builtin_bit_cast(uint32_t, (__builtin_bit_cast(f16x2, p0) - z2) * s2);
    ov.y = __builtin_bit_cast(uint32_t, (__builtin_bit_cast(f16x2, p1) - z2) * s2);
    ov.z = __builtin_bit_cast(uint32_t, (__builtin_bit_cast(f16x2, p2) - z2) * s2);
    ov.w = __builtin_bit_cast(uint32_t, (__builtin_bit_cast(f16x2, p3) - z2) * s2);
    int cdst = (cc & ~3) | ((cc & 3) ^ ((o >> 1) & 3));
    u32x4* dst = reinterpret_cast<u32x4*>(wh + (size_t)o * K + (cdst << 3));
    __builtin_nontemporal_store(ov, dst);
}

// ---------- path 2 GEMM: 8-phase, counted vmcnt, setprio ---------------------
__global__ __launch_bounds__(512, 2) void awq_gemm8_kernel(
    const unsigned short* __restrict__ xh,
    const unsigned short* __restrict__ wh,
    const float* __restrict__ bias,
    float* __restrict__ out,
    int M, int N, int K)
{
    extern __shared__ __align__(16) unsigned short lds[];
    const int HSZ = 256 * 32;                 // 8192 u16 = 16 KB per half-buffer
    unsigned short* HA = lds;                 // [4][HSZ]
    unsigned short* HB = lds + 4 * HSZ;       // [4][HSZ]

    const int tid  = threadIdx.x;
    const int lane = tid & 63;
    const int wave = tid >> 6;
    const int wr   = wave >> 2;               // 0..1: 128-row half of A
    const int wc   = wave & 3;                // 0..3: 64-col quarter of B
    const int lrow = lane & 15;
    const int cswz = (((lane >> 4) ^ ((lrow >> 1) & 3)) << 3);  // elems

    const int cpx = gridDim.x >> 3;
    const int bid = (blockIdx.x & 7) * cpx + (blockIdx.x >> 3);
    const int ntn = N / 256;                  // 16
    const int m0 = (bid / ntn) * 256;
    const int n0 = (bid % ntn) * 256;
    const int NTU = K >> 5;                   // 128 sub-tiles of 32 k

    f32x4 acc[8][4];
    #pragma unroll
    for (int m = 0; m < 8; ++m)
        #pragma unroll
        for (int n = 0; n < 4; ++n)
            #pragma unroll
            for (int e = 0; e < 4; ++e) acc[m][n][e] = 0.f;

    // stage one 256x32 half-buffer: 2 glds per wave (dest = base + lane*16B)
    auto GLDS = [&](const unsigned short* src, int row0, int u, unsigned short* dst) {
        #pragma unroll
        for (int i = 0; i < 2; ++i) {
            int row = wave * 32 + i * 16 + (lane >> 2);
            const unsigned short* g = src + (size_t)(row0 + row) * K + u * 32 + ((lane & 3) << 3);
            unsigned short* d = dst + row * 32 + ((lane & 3) << 3);
            __builtin_amdgcn_global_load_lds(
                (const __attribute__((address_space(1))) unsigned int*)g,
                (__attribute__((address_space(3))) unsigned int*)d, 16, 0, 0);
        }
    };

    f16x8 af[8];

// phase: optionally read af[8] (A sub-tile U), read 2 B frags (n-half NH),
// issue staging statement, then bar | lgkm0 | prio | 16 MFMA | prio | [vm] bar
#define PHASE(U, NH, DO_A, STAGE_STMT, VM_STMT)                               \
    {                                                                         \
        const unsigned short* Ab_ = HA + ((U) & 3) * HSZ;                     \
        const unsigned short* Bb_ = HB + ((U) & 3) * HSZ;                     \
        if (DO_A) {                                                           \
            _Pragma("unroll")                                                 \
            for (int m_ = 0; m_ < 8; ++m_) {                                  \
                int r_ = wr * 128 + m_ * 16 + lrow;                           \
                af[m_] = __builtin_bit_cast(f16x8,                            \
                    *reinterpret_cast<const uint4*>(&Ab_[r_ * 32 + cswz]));   \
            }                                                                 \
        }                                                                     \
        f16x8 bf_[2];                                                         \
        _Pragma("unroll")                                                     \
        for (int j_ = 0; j_ < 2; ++j_) {                                      \
            int r_ = wc * 64 + ((NH) * 2 + j_) * 16 + lrow;                   \
            bf_[j_] = __builtin_bit_cast(f16x8,                               \
                *reinterpret_cast<const uint4*>(&Bb_[r_ * 32 + cswz]));       \
        }                                                                     \
        STAGE_STMT;                                                           \
        __builtin_amdgcn_s_barrier();                                         \
        asm volatile("s_waitcnt lgkmcnt(0)" ::: "memory");                    \
        __builtin_amdgcn_sched_barrier(0);                                    \
        __builtin_amdgcn_s_setprio(1);                                        \
        _Pragma("unroll")                                                     \
        for (int m_ = 0; m_ < 8; ++m_) {                                      \
            acc[m_][(NH)*2+0] = __builtin_amdgcn_mfma_f32_16x16x32_f16(       \
                af[m_], bf_[0], acc[m_][(NH)*2+0], 0, 0, 0);                  \
            acc[m_][(NH)*2+1] = __builtin_amdgcn_mfma_f32_16x16x32_f16(       \
                af[m_], bf_[1], acc[m_][(NH)*2+1], 0, 0, 0);                  \
        }                                                                     \
        __builtin_amdgcn_s_setprio(0);                                        \
        VM_STMT;                                                              \
        __builtin_amdgcn_s_barrier();                                         \
    }

#define VM4  asm volatile("s_waitcnt vmcnt(4)" ::: "memory")
#define VM0  asm volatile("s_waitcnt vmcnt(0)" ::: "memory")

    // ---- prologue: stage sub-tiles 0,1,2 (A+B) = 12 glds; drain; barrier
    GLDS(xh, m0, 0, HA + 0 * HSZ);
    GLDS(wh, n0, 0, HB + 0 * HSZ);
    GLDS(xh, m0, 1, HA + 1 * HSZ);
    GLDS(wh, n0, 1, HB + 1 * HSZ);
    GLDS(xh, m0, 2, HA + 2 * HSZ);
    GLDS(wh, n0, 2, HB + 2 * HSZ);
    asm volatile("s_waitcnt vmcnt(0)" ::: "memory");
    __syncthreads();

    for (int u0 = 0; u0 < NTU; u0 += 4) {
        const bool steady = (u0 + 6 < NTU);   // all 6 in-loop stagings happen
        const bool g4 = (u0 + 4 < NTU);
        const bool g5 = (u0 + 5 < NTU);
        const bool g6 = (u0 + 6 < NTU);

        // p0: compute (u0,nh0); stage A(u0+3) -> HA[(u0+3)&3]
        PHASE(u0, 0, true,
              { GLDS(xh, m0, u0 + 3, HA + ((u0 + 3) & 3) * HSZ); }, )
        // p1: compute (u0,nh1); stage B(u0+3)
        PHASE(u0, 1, false,
              { GLDS(wh, n0, u0 + 3, HB + ((u0 + 3) & 3) * HSZ); }, )
        // p2: compute (u0+1,nh0); stage A(u0+4)
        PHASE(u0 + 1, 0, true,
              { if (g4) GLDS(xh, m0, u0 + 4, HA + ((u0 + 4) & 3) * HSZ); }, )
        // p3: compute (u0+1,nh1); stage B(u0+4); vmcnt
        PHASE(u0 + 1, 1, false,
              { if (g4) GLDS(wh, n0, u0 + 4, HB + ((u0 + 4) & 3) * HSZ); },
              { if (steady) { VM4; } else { VM0; } })
        // p4: compute (u0+2,nh0); stage A(u0+5)
        PHASE(u0 + 2, 0, true,
              { if (g5) GLDS(xh, m0, u0 + 5, HA + ((u0 + 5) & 3) * HSZ); }, )
        // p5: compute (u0+2,nh1); stage B(u0+5)
        PHASE(u0 + 2, 1, false,
              { if (g5) GLDS(wh, n0, u0 + 5, HB + ((u0 + 5) & 3) * HSZ); }, )
        // p6: compute (u0+3,nh0); stage A(u0+6)
        PHASE(u0 + 3, 0, true,
              { if (g6) GLDS(xh, m0, u0 + 6, HA + ((u0 + 6) & 3) * HSZ); }, )
        // p7: compute (u0+3,nh1); stage B(u0+6); vmcnt
        PHASE(u0 + 3, 1, false,
              { if (g6) GLDS(wh, n0, u0 + 6, HB + ((u0 + 6) & 3) * HSZ); },
              { if (steady) { VM4; } else { VM0; } })
    }
#undef PHASE
#undef VM4
#undef VM0

    // epilogue: C frag col=lane&15, row=(lane>>4)*4+e
    const int r4 = (lane >> 4) << 2;
    #pragma unroll
    for (int n = 0; n < 4; ++n) {
        int col = n0 + wc * 64 + n * 16 + lrow;
        float bv = bias[col];
        #pragma unroll
        for (int m = 0; m < 8; ++m) {
            size_t rbase = (size_t)(m0 + wr * 128 + m * 16 + r4) * N + col;
            #pragma unroll
            for (int e = 0; e < 4; ++e)
                __builtin_nontemporal_store(acc[m][n][e] + bv, &out[rbase + (size_t)e * N]);
        }
    }
}

// ================= fallback (ws too small): reg-staged fused ================
#define BM 256
#define BN 256
#define BK 64

__global__ __launch_bounds__(512, 2) void awq_gemm0_kernel(
    const float* __restrict__ x,
    const int*   __restrict__ qw,
    const int*   __restrict__ qz,
    const float* __restrict__ sc,
    const float* __restrict__ bias,
    float*       __restrict__ out,
    int M, int N, int K)
{
    extern __shared__ __align__(16) unsigned short lds[];
    const int ASZ  = BM * BK;
    const int BPSZ = BN * (BK / 8);
    unsigned short* As = lds;
    uint32_t* Bp = reinterpret_cast<uint32_t*>(lds + 2 * ASZ);

    const int tid  = threadIdx.x;
    const int lane = tid & 63;
    const int wave = tid >> 6;
    const int wr   = wave >> 2;
    const int wc   = wave & 3;
    const int lrow = lane & 15;
    const int lko  = (lane >> 4) << 3;
    const int swr  = (lrow & 7) << 3;

    const int cpx = gridDim.x >> 3;
    const int bid = (blockIdx.x & 7) * cpx + (blockIdx.x >> 3);
    const int ntn = N / BN;
    const int m0 = (bid / ntn) * BM;
    const int n0 = (bid % ntn) * BN;

    const int ngrp = K >> 7;
    const int nzw  = ngrp >> 3;
    const int kw   = K >> 3;
    const int NT   = K / BK;

    const int r_s = tid >> 1;
    const int kh  = tid & 1;
    const int sws = (r_s & 7) << 3;

    f32x4 acc[8][4];
    #pragma unroll
    for (int m = 0; m < 8; ++m)
        #pragma unroll
        for (int n = 0; n < 4; ++n)
            #pragma unroll
            for (int e = 0; e < 4; ++e) acc[m][n][e] = 0.f;

    float    sc_pf[4];
    uint32_t zq_pf[4];
    f16x2    ss[4], zz[4];
    auto PFG = [&](int grp) {
        #pragma unroll
        for (int n = 0; n < 4; ++n) {
            int og = n0 + wc * 64 + n * 16 + lrow;
            sc_pf[n] = sc[(size_t)og * ngrp + grp];
            zq_pf[n] = (uint32_t)qz[(size_t)og * nzw + (grp >> 3)];
        }
    };
    auto SETG = [&](int grp) {
        #pragma unroll
        for (int n = 0; n < 4; ++n) {
            _Float16 s = (_Float16)sc_pf[n];
            uint32_t z = (zq_pf[n] >> ((grp & 7) << 2)) & 0xF;
            _Float16 Z = (_Float16)(float)(1024u + z);
            ss[n][0] = s; ss[n][1] = s;
            zz[n][0] = Z; zz[n][1] = Z;
        }
    };

    float4 a32[8];

    auto GLDSB = [&](int kt, uint32_t* Bw) {
        int row = tid >> 1;
        const int* g = qw + (size_t)(n0 + row) * kw + (kt >> 3) + (tid & 1) * 4;
        uint32_t* d = Bw + row * 8 + (tid & 1) * 4;
        __builtin_amdgcn_global_load_lds(
            (const __attribute__((address_space(1))) unsigned int*)g,
            (__attribute__((address_space(3))) unsigned int*)d, 16, 0, 0);
    };
    auto LOADA = [&](int kt) {
        const float* p = x + (size_t)(m0 + r_s) * K + kt + kh * 32;
        #pragma unroll
        for (int i = 0; i < 8; ++i)
            a32[i] = *reinterpret_cast<const float4*>(p + 4 * i);
    };
    auto WA = [&](unsigned short* dst, int c) {
        uint4 o;
        o.x = __builtin_bit_cast(uint32_t, __builtin_amdgcn_cvt_pkrtz(a32[2*c].x, a32[2*c+1].x));
        o.y = __builtin_bit_cast(uint32_t, __builtin_amdgcn_cvt_pkrtz(a32[2*c].y, a32[2*c+1].y));
        o.z = __builtin_bit_cast(uint32_t, __builtin_amdgcn_cvt_pkrtz(a32[2*c].z, a32[2*c+1].z));
        o.w = __builtin_bit_cast(uint32_t, __builtin_amdgcn_cvt_pkrtz(a32[2*c].w, a32[2*c+1].w));
        int kcol = kh * 32 + 8 * c;
        *reinterpret_cast<uint4*>(&dst[r_s * BK + (kcol ^ sws)]) = o;
    };

    f16x8 af[4], bfA[4], bfB[4];
    auto RDA = [&](const unsigned short* Ab, int mh, int kk) {
        #pragma unroll
        for (int m = 0; m < 4; ++m) {
            int arow = wr * 128 + (mh * 4 + m) * 16 + lrow;
            int idx = arow * BK + ((kk * 32 + lko) ^ swr);
            af[m] = __builtin_bit_cast(f16x8, *reinterpret_cast<const uint4*>(&Ab[idx]));
        }
    };
    auto DEQB = [&](const uint32_t* Bpb, f16x8* b, int kk) {
        const int dcol = kk * 4 + (lane >> 4);
        const uint32_t MK = 0x000F000Fu, MG = 0x64006400u;
        #pragma unroll
        for (int n = 0; n < 4; ++n) {
            int brow = wc * 64 + n * 16 + lrow;
            uint32_t u = Bpb[brow * 8 + dcol];
            uint32_t p0 = (u & MK) | MG;
            uint32_t p1 = ((u >> 4) & MK) | MG;
            uint32_t p2 = ((u >> 8) & MK) | MG;
            uint32_t p3 = ((u >> 12) & MK) | MG;
            u32x4 o;
            o.x = __builtin_bit_cast(uint32_t, (__builtin_bit_cast(f16x2, p0) - zz[n]) * ss[n]);
            o.y = __builtin_bit_cast(uint32_t, (__builtin_bit_cast(f16x2, p1) - zz[n]) * ss[n]);
            o.z = __builtin_bit_cast(uint32_t, (__builtin_bit_cast(f16x2, p2) - zz[n]) * ss[n]);
            o.w = __builtin_bit_cast(uint32_t, (__builtin_bit_cast(f16x2, p3) - zz[n]) * ss[n]);
            b[n] = __builtin_bit_cast(f16x8, o);
        }
    };
    auto MFMAQ = [&](f16x8* bf, int mh) {
        #pragma unroll
        for (int m_ = 0; m_ < 4; ++m_)
            #pragma unroll
            for (int n_ = 0; n_ < 4; ++n_)
                acc[mh * 4 + m_][n_] = __builtin_amdgcn_mfma_f32_16x16x32_f16(
                    af[m_], bf[n_], acc[mh * 4 + m_][n_], 0, 0, 0);
    };

    PFG(0);
    GLDSB(0, Bp);
    LOADA(0);
    asm volatile("s_waitcnt vmcnt(0)" ::: "memory");
    #pragma unroll
    for (int c = 0; c < 4; ++c) WA(As, c);
    SETG(0);
    __syncthreads();

    for (int t = 0; t < NT; ++t) {
        const int grp = t >> 1;
        if (t && !(t & 1)) SETG(grp);
        if ((t & 1) && grp + 1 < ngrp) PFG(grp + 1);

        const int buf = t & 1;
        const unsigned short* Ab = As + buf * ASZ;
        const uint32_t* Bpb = Bp + buf * BPSZ;
        if (t + 1 < NT) {
            GLDSB((t + 1) * BK, Bp + (buf ^ 1) * BPSZ);
            LOADA((t + 1) * BK);
        }

        DEQB(Bpb, bfA, 0);
        RDA(Ab, 0, 0);
        MFMAQ(bfA, 0);
        RDA(Ab, 1, 0);
        MFMAQ(bfA, 1);
        DEQB(Bpb, bfB, 1);
        RDA(Ab, 0, 1);
        MFMAQ(bfB, 0);
        RDA(Ab, 1, 1);
        MFMAQ(bfB, 1);

        if (t + 1 < NT) { WA(As + (buf ^ 1) * ASZ, 0); WA(As + (buf ^ 1) * ASZ, 1);
                          WA(As + (buf ^ 1) * ASZ, 2); WA(As + (buf ^ 1) * ASZ, 3); }
        __syncthreads();
    }

    const int r4 = (lane >> 4) << 2;
    #pragma unroll
    for (int n = 0; n < 4; ++n) {
        int col = n0 + wc * 64 + n * 16 + lrow;
        float bv = bias[col];
        #pragma unroll
        for (int m = 0; m < 8; ++m) {
            size_t rbase = (size_t)(m0 + wr * 128 + m * 16 + r4) * N + col;
            #pragma unroll
            for (int e = 0; e < 4; ++e)
                __builtin_nontemporal_store(acc[m][n][e] + bv, &out[rbase + (size_t)e * N]);
        }
    }
}

extern "C" void kernel_launch(void* const* d_in, const int* in_sizes, int n_in,
                              void* d_out, int out_size, void* d_ws, size_t ws_size,
                              hipStream_t stream) {
    const float* x   = (const float*)d_in[0];
    const int*   qwp = (const int*)d_in[1];
    const int*   qzp = (const int*)d_in[2];
    const float* scp = (const float*)d_in[3];
    const float* bp  = (const float*)d_in[4];
    float* outp = (float*)d_out;

    const int N = in_sizes[4];                 // 4096 (O)
    const int K = (in_sizes[1] / N) * 8;       // 4096 (I)
    const int M = in_sizes[0] / K;             // 8192 (B)

    dim3 block(512);
    const size_t needX = (size_t)M * K * 2;
    const size_t needW = (size_t)N * K * 2;

    if (ws_size >= needX + needW) {
        unsigned short* xh = (unsigned short*)d_ws;
        unsigned short* wh = xh + (size_t)M * K;
        int ncx = M * (K / 8), ncw = N * (K / 8);
        convert_x2_kernel<<<dim3((ncx + 255) / 256), dim3(256), 0, stream>>>(x, xh, M, K);
        convert_w2_kernel<<<dim3((ncw + 255) / 256), dim3(256), 0, stream>>>(qwp, qzp, scp, wh, N, K);
        dim3 grid2((M / 256) * (N / 256));     // 32*16 = 512
        const int ldsbytes = 8 * 256 * 32 * 2; // 128 KB
        (void)hipFuncSetAttribute(
            reinterpret_cast<const void*>(&awq_gemm8_kernel),
            hipFuncAttributeMaxDynamicSharedMemorySize, ldsbytes);
        awq_gemm8_kernel<<<grid2, block, ldsbytes, stream>>>(xh, wh, bp, outp, M, N, K);
    } else {
        dim3 grid((M / BM) * (N / BN));
        const int ldsbytes = 2 * BM * BK * 2 + 2 * BN * (BK / 8) * 4;
        (void)hipFuncSetAttribute(
            reinterpret_cast<const void*>(&awq_gemm0_kernel),
            hipFuncAttributeMaxDynamicSharedMemorySize, ldsbytes);
        awq_gemm0_kernel<<<grid, block, ldsbytes, stream>>>(
            x, qwp, qzp, scp, bp, outp, M, N, K);
    }
}

// Round 18
// 316.139 us; speedup vs baseline: 4.2025x; 1.2882x over previous
//
#include <hip/hip_runtime.h>
#include <stdint.h>

// AWQ 4-bit dequant GEMM: out[M,N] = x[M,K] @ W[N,K]^T + bias
// Path 2 (ws >= X+W): prepass x->fp16 and W->fp16 (dequant) into d_ws
//   (R12-verified layout: row-major, pair-permuted, period-4 swizzle in
//   32-k windows). GEMM: BM=BN=256, 512 thr (8 waves 2Mx4N, 128x64/wave),
//   SYNC PER 64-k TILE (2 sub-tiles of 32 k per sync): per tile, issue all
//   8 glds/wave for t+1 at tile START (full-tile latency cover), compute
//   2 substeps (R12 frag addressing per [256][32] subtile -> 0 conflicts),
//   ONE __syncthreads at tile end (drain is cheap: loads in flight ~2500cyc).
//   LDS = 2 buf x (2 A-sub + 2 B-sub) x 16 KB = 128 KB.
//   Rationale: each sync event costs ~700-950 cyc exposed (R12/R17 ladder);
//   halving events per MFMA is the lever that R17's 8-phase inverted.
// Fallback: reg-staged fused kernel (no ws).

typedef _Float16 f16x2 __attribute__((ext_vector_type(2)));
typedef _Float16 f16x8 __attribute__((ext_vector_type(8)));
typedef float f32x4 __attribute__((ext_vector_type(4)));
typedef unsigned int u32x4 __attribute__((ext_vector_type(4)));

// ---------- prepass: x -> fp16 row-major, pair-perm, period-4 swizzle --------
__global__ void convert_x2_kernel(const float* __restrict__ x,
                                  unsigned short* __restrict__ xh,
                                  int M, int K) {
    int g = blockIdx.x * blockDim.x + threadIdx.x;
    int kc = K >> 3;
    if (g >= M * kc) return;
    int r  = g / kc;
    int cc = g - r * kc;
    int csrc = (cc & ~3) | ((cc & 3) ^ ((r >> 1) & 3));
    const float* p = x + (size_t)r * K + (csrc << 3);
    float4 f0 = *reinterpret_cast<const float4*>(p);
    float4 f1 = *reinterpret_cast<const float4*>(p + 4);
    u32x4 o;
    o.x = __builtin_bit_cast(uint32_t, __builtin_amdgcn_cvt_pkrtz(f0.x, f1.x));
    o.y = __builtin_bit_cast(uint32_t, __builtin_amdgcn_cvt_pkrtz(f0.y, f1.y));
    o.z = __builtin_bit_cast(uint32_t, __builtin_amdgcn_cvt_pkrtz(f0.z, f1.z));
    o.w = __builtin_bit_cast(uint32_t, __builtin_amdgcn_cvt_pkrtz(f0.w, f1.w));
    u32x4* dst = reinterpret_cast<u32x4*>(xh + (size_t)r * K + (cc << 3));
    __builtin_nontemporal_store(o, dst);
}

// ---------- prepass: W int4 -> fp16 dequant, same layout ---------------------
__global__ void convert_w2_kernel(const int* __restrict__ qw,
                                  const int* __restrict__ qz,
                                  const float* __restrict__ sc,
                                  unsigned short* __restrict__ wh,
                                  int Nrows, int K) {
    int g = blockIdx.x * blockDim.x + threadIdx.x;
    int kc = K >> 3;
    if (g >= Nrows * kc) return;
    int o  = g / kc;
    int cc = g - o * kc;
    int ngrp = K >> 7, nzw = ngrp >> 3;
    int grp = cc >> 4;
    float s = sc[(size_t)o * ngrp + grp];
    uint32_t z = ((uint32_t)qz[(size_t)o * nzw + (grp >> 3)] >> ((grp & 7) << 2)) & 0xF;
    uint32_t u = (uint32_t)qw[(size_t)o * kc + cc];
    _Float16 hs = (_Float16)s;
    _Float16 hz = (_Float16)(1024.0f + (float)z);   // integer <=1039: exact fp16
    f16x2 s2 = {hs, hs}, z2 = {hz, hz};
    const uint32_t MK = 0x000F000Fu, MG = 0x64006400u;
    uint32_t p0 = (u & MK) | MG;
    uint32_t p1 = ((u >> 4) & MK) | MG;
    uint32_t p2 = ((u >> 8) & MK) | MG;
    uint32_t p3 = ((u >> 12) & MK) | MG;
    u32x4 ov;
    ov.x = __builtin_bit_cast(uint32_t, (__builtin_bit_cast(f16x2, p0) - z2) * s2);
    ov.y = __builtin_bit_cast(uint32_t, (__builtin_bit_cast(f16x2, p1) - z2) * s2);
    ov.z = __builtin_bit_cast(uint32_t, (__builtin_bit_cast(f16x2, p2) - z2) * s2);
    ov.w = __builtin_bit_cast(uint32_t, (__builtin_bit_cast(f16x2, p3) - z2) * s2);
    int cdst = (cc & ~3) | ((cc & 3) ^ ((o >> 1) & 3));
    u32x4* dst = reinterpret_cast<u32x4*>(wh + (size_t)o * K + (cdst << 3));
    __builtin_nontemporal_store(ov, dst);
}

// ---------- path 2 GEMM: 64-k tiles, one sync/tile, loads issued early -------
__global__ __launch_bounds__(512, 2) void awq_gemm64_kernel(
    const unsigned short* __restrict__ xh,
    const unsigned short* __restrict__ wh,
    const float* __restrict__ bias,
    float* __restrict__ out,
    int M, int N, int K)
{
    extern __shared__ __align__(16) unsigned short lds[];
    const int TSZ = 256 * 32;                 // 8192 u16 = 16 KB per subtile
    // layout: A: [buf][sub] at (buf*2+sub)*TSZ ; B after 4*TSZ
    unsigned short* AB = lds;                 // A region [2][2][TSZ]
    unsigned short* BB = lds + 4 * TSZ;       // B region [2][2][TSZ]

    const int tid  = threadIdx.x;
    const int lane = tid & 63;
    const int wave = tid >> 6;
    const int wr   = wave >> 2;               // 0..1: 128-row half of A
    const int wc   = wave & 3;                // 0..3: 64-col quarter of B
    const int lrow = lane & 15;
    const int cswz = (((lane >> 4) ^ ((lrow >> 1) & 3)) << 3);  // elems

    const int cpx = gridDim.x >> 3;
    const int bid = (blockIdx.x & 7) * cpx + (blockIdx.x >> 3);
    const int ntn = N / 256;                  // 16
    const int m0 = (bid / ntn) * 256;
    const int n0 = (bid % ntn) * 256;
    const int NT = K >> 6;                    // 64 tiles of 64 k

    f32x4 acc[8][4];
    #pragma unroll
    for (int m = 0; m < 8; ++m)
        #pragma unroll
        for (int n = 0; n < 4; ++n)
            #pragma unroll
            for (int e = 0; e < 4; ++e) acc[m][n][e] = 0.f;

    // stage one 256x32 subtile (16 KB): 2 glds per thread (R12-verified map)
    auto GLDS = [&](const unsigned short* src, int row0, int kt, unsigned short* dst) {
        #pragma unroll
        for (int i = 0; i < 2; ++i) {
            int row = wave * 32 + i * 16 + (lane >> 2);
            const unsigned short* g = src + (size_t)(row0 + row) * K + kt + ((lane & 3) << 3);
            unsigned short* d = dst + row * 32 + ((lane & 3) << 3);
            __builtin_amdgcn_global_load_lds(
                (const __attribute__((address_space(1))) unsigned int*)g,
                (__attribute__((address_space(3))) unsigned int*)d, 16, 0, 0);
        }
    };
    // stage full 64-k tile t into buffer b: A sub0, A sub1, B sub0, B sub1
    auto STAGE = [&](int t, int b) {
        GLDS(xh, m0, t * 64,      AB + (b * 2 + 0) * TSZ);
        GLDS(xh, m0, t * 64 + 32, AB + (b * 2 + 1) * TSZ);
        GLDS(wh, n0, t * 64,      BB + (b * 2 + 0) * TSZ);
        GLDS(wh, n0, t * 64 + 32, BB + (b * 2 + 1) * TSZ);
    };

    // ---- prologue: stage tile 0 into buf 0; drain; barrier
    STAGE(0, 0);
    asm volatile("s_waitcnt vmcnt(0)" ::: "memory");
    __syncthreads();

    for (int t = 0; t < NT; ++t) {
        const int buf = t & 1;
        // issue next tile's loads FIRST: full MFMA phase (~2500 cyc) to land
        if (t + 1 < NT) STAGE(t + 1, buf ^ 1);

        #pragma unroll
        for (int sub = 0; sub < 2; ++sub) {
            const unsigned short* Ab = AB + (buf * 2 + sub) * TSZ;
            const unsigned short* Bb = BB + (buf * 2 + sub) * TSZ;
            f16x8 bf[4], af[8];
            #pragma unroll
            for (int n = 0; n < 4; ++n) {
                int row = wc * 64 + n * 16 + lrow;
                bf[n] = __builtin_bit_cast(f16x8,
                        *reinterpret_cast<const uint4*>(&Bb[row * 32 + cswz]));
            }
            #pragma unroll
            for (int m = 0; m < 8; ++m) {
                int row = wr * 128 + m * 16 + lrow;
                af[m] = __builtin_bit_cast(f16x8,
                        *reinterpret_cast<const uint4*>(&Ab[row * 32 + cswz]));
            }
            #pragma unroll
            for (int m = 0; m < 8; ++m)
                #pragma unroll
                for (int n = 0; n < 4; ++n)
                    acc[m][n] = __builtin_amdgcn_mfma_f32_16x16x32_f16(
                        af[m], bf[n], acc[m][n], 0, 0, 0);
        }

        // ONE sync per 64-k tile: drains vmcnt (t+1 glds visibility, mostly
        // landed already) + lgkm, then barrier.
        __syncthreads();
    }

    // epilogue: C frag col=lane&15, row=(lane>>4)*4+e
    const int r4 = (lane >> 4) << 2;
    #pragma unroll
    for (int n = 0; n < 4; ++n) {
        int col = n0 + wc * 64 + n * 16 + lrow;
        float bv = bias[col];
        #pragma unroll
        for (int m = 0; m < 8; ++m) {
            size_t rbase = (size_t)(m0 + wr * 128 + m * 16 + r4) * N + col;
            #pragma unroll
            for (int e = 0; e < 4; ++e)
                __builtin_nontemporal_store(acc[m][n][e] + bv, &out[rbase + (size_t)e * N]);
        }
    }
}

// ================= fallback (ws too small): reg-staged fused ================
#define BM 256
#define BN 256
#define BK 64

__global__ __launch_bounds__(512, 2) void awq_gemm0_kernel(
    const float* __restrict__ x,
    const int*   __restrict__ qw,
    const int*   __restrict__ qz,
    const float* __restrict__ sc,
    const float* __restrict__ bias,
    float*       __restrict__ out,
    int M, int N, int K)
{
    extern __shared__ __align__(16) unsigned short lds[];
    const int ASZ  = BM * BK;
    const int BPSZ = BN * (BK / 8);
    unsigned short* As = lds;
    uint32_t* Bp = reinterpret_cast<uint32_t*>(lds + 2 * ASZ);

    const int tid  = threadIdx.x;
    const int lane = tid & 63;
    const int wave = tid >> 6;
    const int wr   = wave >> 2;
    const int wc   = wave & 3;
    const int lrow = lane & 15;
    const int lko  = (lane >> 4) << 3;
    const int swr  = (lrow & 7) << 3;

    const int cpx = gridDim.x >> 3;
    const int bid = (blockIdx.x & 7) * cpx + (blockIdx.x >> 3);
    const int ntn = N / BN;
    const int m0 = (bid / ntn) * BM;
    const int n0 = (bid % ntn) * BN;

    const int ngrp = K >> 7;
    const int nzw  = ngrp >> 3;
    const int kw   = K >> 3;
    const int NT   = K / BK;

    const int r_s = tid >> 1;
    const int kh  = tid & 1;
    const int sws = (r_s & 7) << 3;

    f32x4 acc[8][4];
    #pragma unroll
    for (int m = 0; m < 8; ++m)
        #pragma unroll
        for (int n = 0; n < 4; ++n)
            #pragma unroll
            for (int e = 0; e < 4; ++e) acc[m][n][e] = 0.f;

    float    sc_pf[4];
    uint32_t zq_pf[4];
    f16x2    ss[4], zz[4];
    auto PFG = [&](int grp) {
        #pragma unroll
        for (int n = 0; n < 4; ++n) {
            int og = n0 + wc * 64 + n * 16 + lrow;
            sc_pf[n] = sc[(size_t)og * ngrp + grp];
            zq_pf[n] = (uint32_t)qz[(size_t)og * nzw + (grp >> 3)];
        }
    };
    auto SETG = [&](int grp) {
        #pragma unroll
        for (int n = 0; n < 4; ++n) {
            _Float16 s = (_Float16)sc_pf[n];
            uint32_t z = (zq_pf[n] >> ((grp & 7) << 2)) & 0xF;
            _Float16 Z = (_Float16)(float)(1024u + z);
            ss[n][0] = s; ss[n][1] = s;
            zz[n][0] = Z; zz[n][1] = Z;
        }
    };

    float4 a32[8];

    auto GLDSB = [&](int kt, uint32_t* Bw) {
        int row = tid >> 1;
        const int* g = qw + (size_t)(n0 + row) * kw + (kt >> 3) + (tid & 1) * 4;
        uint32_t* d = Bw + row * 8 + (tid & 1) * 4;
        __builtin_amdgcn_global_load_lds(
            (const __attribute__((address_space(1))) unsigned int*)g,
            (__attribute__((address_space(3))) unsigned int*)d, 16, 0, 0);
    };
    auto LOADA = [&](int kt) {
        const float* p = x + (size_t)(m0 + r_s) * K + kt + kh * 32;
        #pragma unroll
        for (int i = 0; i < 8; ++i)
            a32[i] = *reinterpret_cast<const float4*>(p + 4 * i);
    };
    auto WA = [&](unsigned short* dst, int c) {
        uint4 o;
        o.x = __builtin_bit_cast(uint32_t, __builtin_amdgcn_cvt_pkrtz(a32[2*c].x, a32[2*c+1].x));
        o.y = __builtin_bit_cast(uint32_t, __builtin_amdgcn_cvt_pkrtz(a32[2*c].y, a32[2*c+1].y));
        o.z = __builtin_bit_cast(uint32_t, __builtin_amdgcn_cvt_pkrtz(a32[2*c].z, a32[2*c+1].z));
        o.w = __builtin_bit_cast(uint32_t, __builtin_amdgcn_cvt_pkrtz(a32[2*c].w, a32[2*c+1].w));
        int kcol = kh * 32 + 8 * c;
        *reinterpret_cast<uint4*>(&dst[r_s * BK + (kcol ^ sws)]) = o;
    };

    f16x8 af[4], bfA[4], bfB[4];
    auto RDA = [&](const unsigned short* Ab, int mh, int kk) {
        #pragma unroll
        for (int m = 0; m < 4; ++m) {
            int arow = wr * 128 + (mh * 4 + m) * 16 + lrow;
            int idx = arow * BK + ((kk * 32 + lko) ^ swr);
            af[m] = __builtin_bit_cast(f16x8, *reinterpret_cast<const uint4*>(&Ab[idx]));
        }
    };
    auto DEQB = [&](const uint32_t* Bpb, f16x8* b, int kk) {
        const int dcol = kk * 4 + (lane >> 4);
        const uint32_t MK = 0x000F000Fu, MG = 0x64006400u;
        #pragma unroll
        for (int n = 0; n < 4; ++n) {
            int brow = wc * 64 + n * 16 + lrow;
            uint32_t u = Bpb[brow * 8 + dcol];
            uint32_t p0 = (u & MK) | MG;
            uint32_t p1 = ((u >> 4) & MK) | MG;
            uint32_t p2 = ((u >> 8) & MK) | MG;
            uint32_t p3 = ((u >> 12) & MK) | MG;
            u32x4 o;
            o.x = __builtin_bit_cast(uint32_t, (__builtin_bit_cast(f16x2, p0) - zz[n]) * ss[n]);
            o.y = __builtin_bit_cast(uint32_t, (__builtin_bit_cast(f16x2, p1) - zz[n]) * ss[n]);
            o.z = __builtin_bit_cast(uint32_t, (__builtin_bit_cast(f16x2, p2) - zz[n]) * ss[n]);
            o.w = __builtin_bit_cast(uint32_t, (__builtin_bit_cast(f16x2, p3) - zz[n]) * ss[n]);
            b[n] = __builtin_bit_cast(f16x8, o);
        }
    };
    auto MFMAQ = [&](f16x8* bf, int mh) {
        #pragma unroll
        for (int m_ = 0; m_ < 4; ++m_)
            #pragma unroll
            for (int n_ = 0; n_ < 4; ++n_)
                acc[mh * 4 + m_][n_] = __builtin_amdgcn_mfma_f32_16x16x32_f16(
                    af[m_], bf[n_], acc[mh * 4 + m_][n_], 0, 0, 0);
    };

    PFG(0);
    GLDSB(0, Bp);
    LOADA(0);
    asm volatile("s_waitcnt vmcnt(0)" ::: "memory");
    #pragma unroll
    for (int c = 0; c < 4; ++c) WA(As, c);
    SETG(0);
    __syncthreads();

    for (int t = 0; t < NT; ++t) {
        const int grp = t >> 1;
        if (t && !(t & 1)) SETG(grp);
        if ((t & 1) && grp + 1 < ngrp) PFG(grp + 1);

        const int buf = t & 1;
        const unsigned short* Ab = As + buf * ASZ;
        const uint32_t* Bpb = Bp + buf * BPSZ;
        if (t + 1 < NT) {
            GLDSB((t + 1) * BK, Bp + (buf ^ 1) * BPSZ);
            LOADA((t + 1) * BK);
        }

        DEQB(Bpb, bfA, 0);
        RDA(Ab, 0, 0);
        MFMAQ(bfA, 0);
        RDA(Ab, 1, 0);
        MFMAQ(bfA, 1);
        DEQB(Bpb, bfB, 1);
        RDA(Ab, 0, 1);
        MFMAQ(bfB, 0);
        RDA(Ab, 1, 1);
        MFMAQ(bfB, 1);

        if (t + 1 < NT) { WA(As + (buf ^ 1) * ASZ, 0); WA(As + (buf ^ 1) * ASZ, 1);
                          WA(As + (buf ^ 1) * ASZ, 2); WA(As + (buf ^ 1) * ASZ, 3); }
        __syncthreads();
    }

    const int r4 = (lane >> 4) << 2;
    #pragma unroll
    for (int n = 0; n < 4; ++n) {
        int col = n0 + wc * 64 + n * 16 + lrow;
        float bv = bias[col];
        #pragma unroll
        for (int m = 0; m < 8; ++m) {
            size_t rbase = (size_t)(m0 + wr * 128 + m * 16 + r4) * N + col;
            #pragma unroll
            for (int e = 0; e < 4; ++e)
                __builtin_nontemporal_store(acc[m][n][e] + bv, &out[rbase + (size_t)e * N]);
        }
    }
}

extern "C" void kernel_launch(void* const* d_in, const int* in_sizes, int n_in,
                              void* d_out, int out_size, void* d_ws, size_t ws_size,
                              hipStream_t stream) {
    const float* x   = (const float*)d_in[0];
    const int*   qwp = (const int*)d_in[1];
    const int*   qzp = (const int*)d_in[2];
    const float* scp = (const float*)d_in[3];
    const float* bp  = (const float*)d_in[4];
    float* outp = (float*)d_out;

    const int N = in_sizes[4];                 // 4096 (O)
    const int K = (in_sizes[1] / N) * 8;       // 4096 (I)
    const int M = in_sizes[0] / K;             // 8192 (B)

    dim3 block(512);
    const size_t needX = (size_t)M * K * 2;
    const size_t needW = (size_t)N * K * 2;

    if (ws_size >= needX + needW) {
        unsigned short* xh = (unsigned short*)d_ws;
        unsigned short* wh = xh + (size_t)M * K;
        int ncx = M * (K / 8), ncw = N * (K / 8);
        convert_x2_kernel<<<dim3((ncx + 255) / 256), dim3(256), 0, stream>>>(x, xh, M, K);
        convert_w2_kernel<<<dim3((ncw + 255) / 256), dim3(256), 0, stream>>>(qwp, qzp, scp, wh, N, K);
        dim3 grid2((M / 256) * (N / 256));     // 32*16 = 512
        const int ldsbytes = 8 * 256 * 32 * 2; // 128 KB
        (void)hipFuncSetAttribute(
            reinterpret_cast<const void*>(&awq_gemm64_kernel),
            hipFuncAttributeMaxDynamicSharedMemorySize, ldsbytes);
        awq_gemm64_kernel<<<grid2, block, ldsbytes, stream>>>(xh, wh, bp, outp, M, N, K);
    } else {
        dim3 grid((M / BM) * (N / BN));
        const int ldsbytes = 2 * BM * BK * 2 + 2 * BN * (BK / 8) * 4;
        (void)hipFuncSetAttribute(
            reinterpret_cast<const void*>(&awq_gemm0_kernel),
            hipFuncAttributeMaxDynamicSharedMemorySize, ldsbytes);
        awq_gemm0_kernel<<<grid, block, ldsbytes, stream>>>(
            x, qwp, qzp, scp, bp, outp, M, N, K);
    }
}